// Round 5
// baseline (347.969 us; speedup 1.0000x reference)
//
#include <hip/hip_runtime.h>
#include <math.h>

#define L3 2197            // 13^3
#define NROW 169           // 13*13 rows per volume
#define NC 338             // uint4 chunks per padded bf16 volume (169 rows * 16 bf16 / 8)
#define RP 20              // LDS row pitch (floats): c-len up to 17, padded
#define AP 344             // LDS a-slab stride (floats): 17 rows * 20 + 4 slack, 16B-aligned
#define RSZ 5844           // 16*344 + 16*20 + 17, rounded -> 23376 B
#define NTS 320            // smooth kernels: 5 waves, all pencil stages single-pass (max 289)
#define NTO 384            // k_out: 6 waves, 338 chunks single-pass

typedef unsigned int u32;

// round-to-nearest-even bf16 pack of two floats -> one u32 (lo = a, hi = b)
__device__ __forceinline__ u32 pack2bf(float a, float b) {
    u32 ua = __float_as_uint(a);
    u32 ub = __float_as_uint(b);
    ua = (ua + 0x7fffu + ((ua >> 16) & 1u)) >> 16;
    ub = (ub + 0x7fffu + ((ub >> 16) & 1u)) & 0xffff0000u;
    return ua | ub;
}

__device__ __forceinline__ void unpack8(uint4 v, float* f) {
    f[0] = __uint_as_float(v.x << 16);
    f[1] = __uint_as_float(v.x & 0xffff0000u);
    f[2] = __uint_as_float(v.y << 16);
    f[3] = __uint_as_float(v.y & 0xffff0000u);
    f[4] = __uint_as_float(v.z << 16);
    f[5] = __uint_as_float(v.z & 0xffff0000u);
    f[6] = __uint_as_float(v.w << 16);
    f[7] = __uint_as_float(v.w & 0xffff0000u);
}

__device__ __forceinline__ uint4 pack8(const float* f) {
    uint4 v;
    v.x = pack2bf(f[0], f[1]);
    v.y = pack2bf(f[2], f[3]);
    v.z = pack2bf(f[4], f[5]);
    v.w = pack2bf(f[6], f[7]);
    return v;
}

// Sliding clamped max-of-3 (edge-pad 3 + maxpool3 VALID): x[13] -> o[17]
__device__ __forceinline__ void maxpool_row(const float* x, float* o) {
    float p[12];
#pragma unroll
    for (int i = 0; i < 12; ++i) p[i] = fmaxf(x[i], x[i + 1]);
    o[0] = x[0];
    o[1] = x[0];
    o[2] = p[0];
#pragma unroll
    for (int j = 3; j <= 13; ++j) o[j] = fmaxf(p[j - 3], x[j - 1]);
    o[14] = p[11];
    o[15] = x[12];
    o[16] = x[12];
}

// Two stacked avgpool3 == 5-tap triangle [1,2,3,2,1] (scale applied): y[17] -> o[13]
__device__ __forceinline__ void tri_row(const float* y, float* o, float scale) {
#pragma unroll
    for (int c = 0; c < 13; ++c) {
        float s = fmaf(2.0f, y[c + 1], y[c]);
        s = fmaf(3.0f, y[c + 2], s);
        s = fmaf(2.0f, y[c + 3], s);
        o[c] = (s + y[c + 4]) * scale;
    }
}

// In-place smooth over padded-row LDS buffer R.
// Input: (a13,b13,c13) at rows R[a*AP + b*RP + 0..12]. Output: same slots.
// Order: max_c, max_b, (max_a+conv_a fused), conv_b, conv_c. Valid because all
// maxes precede all convs and convs commute among themselves.
__device__ void smooth_R(float* R, int tid) {
    // M1: c-axis max, in-place per row (c 13 -> 17 inside pitch-20 row)
    if (tid < NROW) {
        int a = tid / 13, b = tid - 13 * a;
        float* row = R + a * AP + b * RP;
        float x[13], o[17];
        float4 v0 = *(const float4*)row;
        float4 v1 = *(const float4*)(row + 4);
        float4 v2 = *(const float4*)(row + 8);
        x[0] = v0.x; x[1] = v0.y; x[2] = v0.z; x[3] = v0.w;
        x[4] = v1.x; x[5] = v1.y; x[6] = v1.z; x[7] = v1.w;
        x[8] = v2.x; x[9] = v2.y; x[10] = v2.z; x[11] = v2.w;
        x[12] = row[12];
        maxpool_row(x, o);
        *(float4*)row       = make_float4(o[0], o[1], o[2], o[3]);
        *(float4*)(row + 4) = make_float4(o[4], o[5], o[6], o[7]);
        *(float4*)(row + 8) = make_float4(o[8], o[9], o[10], o[11]);
        *(float4*)(row + 12) = make_float4(o[12], o[13], o[14], o[15]);
        row[16] = o[16];
    }
    __syncthreads();
    // M2: b-axis max, in-place per (a,c) column (b 13 -> 17, stride RP)
    if (tid < 221) {
        int a = tid / 17, c = tid - 17 * a;
        float* base = R + a * AP + c;
        float x[13], o[17];
#pragma unroll
        for (int i = 0; i < 13; ++i) x[i] = base[i * RP];
        maxpool_row(x, o);
#pragma unroll
        for (int i = 0; i < 17; ++i) base[i * RP] = o[i];
    }
    __syncthreads();
    // M3 + C_a fused: a-axis max (13->17) then a-axis conv (17->13), in regs,
    // in-place per (b,c) column (stride AP)
    if (tid < 289) {
        int b = tid / 17, c = tid - 17 * b;
        float* base = R + b * RP + c;
        float x[13], m[17], o[13];
#pragma unroll
        for (int i = 0; i < 13; ++i) x[i] = base[i * AP];
        maxpool_row(x, m);
        tri_row(m, o, 1.0f);
#pragma unroll
        for (int i = 0; i < 13; ++i) base[i * AP] = o[i];
    }
    __syncthreads();
    // C_b: b-axis conv (17 -> 13), in-place per (a,c) column, a now 0..12
    if (tid < 221) {
        int a = tid / 17, c = tid - 17 * a;
        float* base = R + a * AP + c;
        float y[17], o[13];
#pragma unroll
        for (int i = 0; i < 17; ++i) y[i] = base[i * RP];
        tri_row(y, o, 1.0f);
#pragma unroll
        for (int i = 0; i < 13; ++i) base[i * RP] = o[i];
    }
    __syncthreads();
    // C_c: c-axis conv (17 -> 13), in-place per row, final scale 1/729
    if (tid < NROW) {
        int a = tid / 13, b = tid - 13 * a;
        float* row = R + a * AP + b * RP;
        float y[17], o[13];
        float4 v0 = *(const float4*)row;
        float4 v1 = *(const float4*)(row + 4);
        float4 v2 = *(const float4*)(row + 8);
        float4 v3 = *(const float4*)(row + 12);
        y[0] = v0.x; y[1] = v0.y; y[2] = v0.z; y[3] = v0.w;
        y[4] = v1.x; y[5] = v1.y; y[6] = v1.z; y[7] = v1.w;
        y[8] = v2.x; y[9] = v2.y; y[10] = v2.z; y[11] = v2.w;
        y[12] = v3.x; y[13] = v3.y; y[14] = v3.z; y[15] = v3.w;
        y[16] = row[16];
        tri_row(y, o, 1.0f / 729.0f);
        *(float4*)row       = make_float4(o[0], o[1], o[2], o[3]);
        *(float4*)(row + 4) = make_float4(o[4], o[5], o[6], o[7]);
        *(float4*)(row + 8) = make_float4(o[8], o[9], o[10], o[11]);
        row[12] = o[12];
    }
    __syncthreads();
}

// Pack R rows (13 valid floats) -> padded bf16 volume chunks (pads = 0)
__device__ __forceinline__ void pack_rows(const float* R, uint4* dst, int tid, int nt) {
    for (int j = tid; j < NC; j += nt) {
        int r = j >> 1, h = j & 1;
        int a = r / 13, b = r - 13 * a;
        const float* p = R + a * AP + b * RP + h * 8;
        float4 u = *(const float4*)p;
        float4 v = *(const float4*)(p + 4);
        float f[8] = {u.x, u.y, u.z, u.w, v.x, v.y, v.z, v.w};
        if (h) { f[5] = 0.0f; f[6] = 0.0f; f[7] = 0.0f; }  // c >= 13 pads
        dst[j] = pack8(f);
    }
}

// tmp1 = smooth(a1 + a0*cost) [padded bf16]; preA = a4 + a2*(a1+a0*cost) [padded bf16]
__global__ __launch_bounds__(NTS) void k_smooth1(
        const float* __restrict__ cost, const float* __restrict__ alpha,
        uint4* __restrict__ tmp1, uint4* __restrict__ preA) {
    __shared__ alignas(16) float R[RSZ];
    const int n = blockIdx.x;
    const int tid = threadIdx.x;
    const float a0 = alpha[0], a1 = alpha[1], a2 = alpha[2], a4 = alpha[4];
    const float* src = cost + (size_t)n * L3;
    uint4* pre = preA + (size_t)n * NC;
    for (int j = tid; j < NC; j += NTS) {
        int r = j >> 1, h = j & 1;
        int a = r / 13, b = r - 13 * a;
        const int gbase = r * 13 + h * 8;
        float f[8], g[8];
#pragma unroll
        for (int t = 0; t < 8; ++t) {
            const int c = h * 8 + t;
            f[t] = (c < 13) ? fmaf(a0, src[gbase + t], a1) : 0.0f;
            g[t] = (c < 13) ? fmaf(a2, f[t], a4) : 0.0f;
        }
        float* p = R + a * AP + b * RP + h * 8;
        *(float4*)p       = make_float4(f[0], f[1], f[2], f[3]);
        *(float4*)(p + 4) = make_float4(f[4], f[5], f[6], f[7]);
        pre[j] = pack8(g);
    }
    __syncthreads();
    smooth_R(R, tid);
    pack_rows(R, tmp1 + (size_t)n * NC, tid, NTS);
}

// tmp2 = smooth(preA + (a3/norm) * sum_k w_k * tmp1[knn_k]) [padded bf16]
__global__ __launch_bounds__(NTS) void k_mid(
        const int* __restrict__ knn, const float* __restrict__ dist,
        const float* __restrict__ alpha, const uint4* __restrict__ tmp1,
        const uint4* __restrict__ preA, uint4* __restrict__ tmp2, int K) {
    __shared__ alignas(16) float R[RSZ];
    __shared__ float s_w[8];
    const int n = blockIdx.x;
    const int tid = threadIdx.x;
    if (tid < K) s_w[tid] = expf(-dist[n * K + tid] * (1.0f / 200.0f));
    __syncthreads();
    float norm = 0.0f;
    for (int k = 0; k < K; ++k) norm += s_w[k];
    const float sc = alpha[3] / norm;

    const uint4* ptr[8];
    float wk[8];
    for (int k = 0; k < K; ++k) {
        ptr[k] = tmp1 + (size_t)knn[n * K + k] * NC;
        wk[k] = s_w[k];
    }
    const uint4* pre = preA + (size_t)n * NC;
    for (int j = tid; j < NC; j += NTS) {
        float f[8], acc[8], g[8];
        unpack8(pre[j], f);
#pragma unroll
        for (int t = 0; t < 8; ++t) acc[t] = 0.0f;
#pragma unroll 8
        for (int k = 0; k < K; ++k) {
            unpack8(ptr[k][j], g);
#pragma unroll
            for (int t = 0; t < 8; ++t) acc[t] = fmaf(wk[k], g[t], acc[t]);
        }
        const int r = j >> 1, h = j & 1;
        const int a = r / 13, b = r - 13 * a;
        float* p = R + a * AP + b * RP + h * 8;
        *(float4*)p = make_float4(fmaf(sc, acc[0], f[0]), fmaf(sc, acc[1], f[1]),
                                  fmaf(sc, acc[2], f[2]), fmaf(sc, acc[3], f[3]));
        *(float4*)(p + 4) = make_float4(fmaf(sc, acc[4], f[4]), fmaf(sc, acc[5], f[5]),
                                        fmaf(sc, acc[6], f[6]), fmaf(sc, acc[7], f[7]));
    }
    __syncthreads();
    smooth_R(R, tid);
    pack_rows(R, tmp2 + (size_t)n * NC, tid, NTS);
}

// out = (a5/norm) * sum_k w_k * tmp2[knn_k]   (compact fp32 output)
__global__ __launch_bounds__(NTO) void k_out(
        const int* __restrict__ knn, const float* __restrict__ dist,
        const float* __restrict__ alpha, const uint4* __restrict__ tmp2,
        float* __restrict__ out, int K) {
    __shared__ float s_w[8];
    const int n = blockIdx.x;
    const int tid = threadIdx.x;
    if (tid < K) s_w[tid] = expf(-dist[n * K + tid] * (1.0f / 200.0f));
    __syncthreads();
    float norm = 0.0f;
    for (int k = 0; k < K; ++k) norm += s_w[k];
    const float sc = alpha[5] / norm;

    const uint4* ptr[8];
    float wk[8];
    for (int k = 0; k < K; ++k) {
        ptr[k] = tmp2 + (size_t)knn[n * K + k] * NC;
        wk[k] = s_w[k];
    }
    float* dst = out + (size_t)n * L3;
    for (int j = tid; j < NC; j += NTO) {
        float acc[8], g[8];
#pragma unroll
        for (int t = 0; t < 8; ++t) acc[t] = 0.0f;
#pragma unroll 8
        for (int k = 0; k < K; ++k) {
            unpack8(ptr[k][j], g);
#pragma unroll
            for (int t = 0; t < 8; ++t) acc[t] = fmaf(wk[k], g[t], acc[t]);
        }
        const int r = j >> 1, h = j & 1;
        const int gbase = r * 13 + h * 8;
#pragma unroll
        for (int t = 0; t < 8; ++t)
            if (h * 8 + t < 13) dst[gbase + t] = sc * acc[t];
    }
}

extern "C" void kernel_launch(void* const* d_in, const int* in_sizes, int n_in,
                              void* d_out, int out_size, void* d_ws, size_t ws_size,
                              hipStream_t stream) {
    const float* cost  = (const float*)d_in[0];
    const int*   knn   = (const int*)d_in[1];
    const float* dist  = (const float*)d_in[2];
    const float* alpha = (const float*)d_in[3];
    float* out = (float*)d_out;

    const int N = in_sizes[0] / L3;
    int K = in_sizes[1] / N;
    if (K > 8) K = 8;

    // workspace: three padded bf16 volume arrays, each N*NC uint4 (N*5408 bytes)
    uint4* tmp1 = (uint4*)d_ws;
    uint4* tmp2 = tmp1 + (size_t)N * NC;
    uint4* preA = tmp2 + (size_t)N * NC;

    k_smooth1<<<N, NTS, 0, stream>>>(cost, alpha, tmp1, preA);
    k_mid<<<N, NTS, 0, stream>>>(knn, dist, alpha, tmp1, preA, tmp2, K);
    k_out<<<N, NTO, 0, stream>>>(knn, dist, alpha, tmp2, out, K);
}

// Round 6
// 328.376 us; speedup vs baseline: 1.0597x; 1.0597x over previous
//
#include <hip/hip_runtime.h>
#include <math.h>

#define L3 2197            // 13^3
#define SP 2200            // bf16 elems per padded volume (4400 B, 16B-aligned)
#define NV (SP / 8)        // 275 uint4 chunks of 8 bf16
#define NTS 320            // smooth kernels: 5 waves; all pencil stages single-pass
#define NTO 320            // k_out: single-pass over 275 chunks

// Single in-place LDS buffer: peak stage size 17^3
#define SSZ 4913

typedef unsigned int u32;

// round-to-nearest-even bf16 pack of two floats -> one u32 (lo = a, hi = b)
__device__ __forceinline__ u32 pack2bf(float a, float b) {
    u32 ua = __float_as_uint(a);
    u32 ub = __float_as_uint(b);
    ua = (ua + 0x7fffu + ((ua >> 16) & 1u)) >> 16;
    ub = (ub + 0x7fffu + ((ub >> 16) & 1u)) & 0xffff0000u;
    return ua | ub;
}

__device__ __forceinline__ void unpack8(uint4 v, float* f) {
    f[0] = __uint_as_float(v.x << 16);
    f[1] = __uint_as_float(v.x & 0xffff0000u);
    f[2] = __uint_as_float(v.y << 16);
    f[3] = __uint_as_float(v.y & 0xffff0000u);
    f[4] = __uint_as_float(v.z << 16);
    f[5] = __uint_as_float(v.z & 0xffff0000u);
    f[6] = __uint_as_float(v.w << 16);
    f[7] = __uint_as_float(v.w & 0xffff0000u);
}

__device__ __forceinline__ uint4 pack8(const float* f) {
    uint4 v;
    v.x = pack2bf(f[0], f[1]);
    v.y = pack2bf(f[2], f[3]);
    v.z = pack2bf(f[4], f[5]);
    v.w = pack2bf(f[6], f[7]);
    return v;
}

// Sliding clamped max-of-3 (edge-pad 3 + maxpool3 VALID): x[13] -> o[17]
__device__ __forceinline__ void maxpool_row(const float* x, float* o) {
    float p[12];
#pragma unroll
    for (int i = 0; i < 12; ++i) p[i] = fmaxf(x[i], x[i + 1]);
    o[0] = x[0];
    o[1] = x[0];
    o[2] = p[0];
#pragma unroll
    for (int j = 3; j <= 13; ++j) o[j] = fmaxf(p[j - 3], x[j - 1]);
    o[14] = p[11];
    o[15] = x[12];
    o[16] = x[12];
}

// Two stacked avgpool3 == 5-tap triangle [1,2,3,2,1] (scale applied): y[17] -> o[13]
__device__ __forceinline__ void tri_row(const float* y, float* o, float scale) {
#pragma unroll
    for (int c = 0; c < 13; ++c) {
        float s = fmaf(2.0f, y[c + 1], y[c]);
        s = fmaf(3.0f, y[c + 2], s);
        s = fmaf(2.0f, y[c + 3], s);
        o[c] = (s + y[c + 4]) * scale;
    }
}

// S holds (13,13,13) input (c fastest); on return S[0..2196] = smooth(S).
// In-place single-buffer, 5 stages: M_c, M_b, (M_a + C_a fused), C_b, C_c.
// Valid: all maxes precede all convs; convs commute among themselves.
// Stage shapes: 2197 -> 2873 -> 4913 -> (4913, a:17->13 in place) -> 2873 -> 2197
__device__ void smooth_single(float* S, int tid) {
    __syncthreads();   // make caller's fill visible
    // M_c along c: (13,13,13) -> (13,13,17); 169 row pencils
    {
        const bool act = tid < 169;
        float x[13], o[17];
        if (act) {
            const float* src = S + tid * 13;
#pragma unroll
            for (int i = 0; i < 13; ++i) x[i] = src[i];
            maxpool_row(x, o);
        }
        __syncthreads();
        if (act) {
            float* d = S + tid * 17;
#pragma unroll
            for (int i = 0; i < 17; ++i) d[i] = o[i];
        }
        __syncthreads();
    }
    // M_b along b: (13,13,17) -> (13,17,17); 221 pencils (a,c)
    {
        const bool act = tid < 221;
        const int a = tid / 17, c = tid % 17;
        float x[13], o[17];
        if (act) {
            const float* src = S + a * 221 + c;
#pragma unroll
            for (int i = 0; i < 13; ++i) x[i] = src[i * 17];
            maxpool_row(x, o);
        }
        __syncthreads();
        if (act) {
            float* d = S + a * 289 + c;
#pragma unroll
            for (int i = 0; i < 17; ++i) d[i * 17] = o[i];
        }
        __syncthreads();
    }
    // M_a + C_a fused: a-axis max (13->17) then a-axis conv (17->13), all in
    // registers, in-place per (b,c) column (stride 289, own column, no mid-barrier)
    if (tid < 289) {
        float x[13], m[17], o[13];
        const float* src = S + tid;
#pragma unroll
        for (int i = 0; i < 13; ++i) x[i] = src[i * 289];
        maxpool_row(x, m);
        tri_row(m, o, 1.0f);
        float* d = S + tid;
#pragma unroll
        for (int i = 0; i < 13; ++i) d[i * 289] = o[i];
    }
    __syncthreads();
    // C_b along b: (13,17,17) -> (13,13,17); 221 pencils (a,c), a in 0..12
    {
        const bool act = tid < 221;
        const int a = tid / 17, c = tid % 17;
        float y[17], o[13];
        if (act) {
            const float* src = S + a * 289 + c;
#pragma unroll
            for (int i = 0; i < 17; ++i) y[i] = src[i * 17];
            tri_row(y, o, 1.0f);
        }
        __syncthreads();
        if (act) {
            float* d = S + a * 221 + c;
#pragma unroll
            for (int i = 0; i < 13; ++i) d[i * 17] = o[i];
        }
        __syncthreads();
    }
    // C_c along c: (13,13,17) -> (13,13,13); 169 row pencils, scale 1/729
    {
        const bool act = tid < 169;
        float y[17], o[13];
        if (act) {
            const float* src = S + tid * 17;
#pragma unroll
            for (int i = 0; i < 17; ++i) y[i] = src[i];
            tri_row(y, o, 1.0f / 729.0f);
        }
        __syncthreads();
        if (act) {
            float* d = S + tid * 13;
#pragma unroll
            for (int i = 0; i < 13; ++i) d[i] = o[i];
        }
        __syncthreads();
    }
}

// tmp1 = smooth(a1 + a0*cost) as bf16; preA = a4 + a2*(a1 + a0*cost) as bf16
__global__ __launch_bounds__(NTS) void k_smooth1(
        const float* __restrict__ cost, const float* __restrict__ alpha,
        uint4* __restrict__ tmp1, uint4* __restrict__ preA) {
    __shared__ alignas(16) float S[SSZ];
    const int n = blockIdx.x;
    const int tid = threadIdx.x;
    const float a0 = alpha[0], a1 = alpha[1], a2 = alpha[2], a4 = alpha[4];
    const float* src = cost + (size_t)n * L3;
    for (int i = tid; i < L3; i += NTS) S[i] = fmaf(a0, src[i], a1);
    if (tid < SP - L3) S[L3 + tid] = 0.0f;   // pad for pack loop
    __syncthreads();
    uint4* pre = preA + (size_t)n * NV;
    if (tid < NV) {
        float f[8];
#pragma unroll
        for (int j = 0; j < 8; ++j) f[j] = fmaf(a2, S[8 * tid + j], a4);
        pre[tid] = pack8(f);
    }
    smooth_single(S, tid);
    uint4* dst = tmp1 + (size_t)n * NV;
    if (tid < NV) {
        float f[8];
        const int base = 8 * tid;
#pragma unroll
        for (int j = 0; j < 8; ++j) f[j] = (base + j < L3) ? S[base + j] : 0.0f;
        dst[tid] = pack8(f);
    }
}

// tmp2 = smooth(preA + (a3/norm) * sum_k w_k * tmp1[knn_k]) as bf16
__global__ __launch_bounds__(NTS) void k_mid(
        const int* __restrict__ knn, const float* __restrict__ dist,
        const float* __restrict__ alpha, const uint4* __restrict__ tmp1,
        const uint4* __restrict__ preA, uint4* __restrict__ tmp2, int K) {
    __shared__ alignas(16) float S[SSZ];
    __shared__ float s_w[8];
    const int n = blockIdx.x;
    const int tid = threadIdx.x;
    if (tid < K) s_w[tid] = expf(-dist[n * K + tid] * (1.0f / 200.0f));
    __syncthreads();
    float norm = 0.0f;
    for (int k = 0; k < K; ++k) norm += s_w[k];
    const float sc = alpha[3] / norm;

    const uint4* ptr[8];
    float wk[8];
    for (int k = 0; k < K; ++k) {
        ptr[k] = tmp1 + (size_t)knn[n * K + k] * NV;
        wk[k] = s_w[k];
    }
    const uint4* pre = preA + (size_t)n * NV;
    if (tid < NV) {
        float f[8], acc[8], g[8];
        unpack8(pre[tid], f);
#pragma unroll
        for (int j = 0; j < 8; ++j) acc[j] = 0.0f;
#pragma unroll 8
        for (int k = 0; k < K; ++k) {
            unpack8(ptr[k][tid], g);
#pragma unroll
            for (int j = 0; j < 8; ++j) acc[j] = fmaf(wk[k], g[j], acc[j]);
        }
#pragma unroll
        for (int j = 0; j < 8; ++j) S[8 * tid + j] = fmaf(sc, acc[j], f[j]);
    }
    smooth_single(S, tid);
    uint4* dst = tmp2 + (size_t)n * NV;
    if (tid < NV) {
        float f[8];
        const int base = 8 * tid;
#pragma unroll
        for (int j = 0; j < 8; ++j) f[j] = (base + j < L3) ? S[base + j] : 0.0f;
        dst[tid] = pack8(f);
    }
}

// out = (a5/norm) * sum_k w_k * tmp2[knn_k]   (fp32 output)
__global__ __launch_bounds__(NTO) void k_out(
        const int* __restrict__ knn, const float* __restrict__ dist,
        const float* __restrict__ alpha, const uint4* __restrict__ tmp2,
        float* __restrict__ out, int K) {
    __shared__ float s_w[8];
    const int n = blockIdx.x;
    const int tid = threadIdx.x;
    if (tid < K) s_w[tid] = expf(-dist[n * K + tid] * (1.0f / 200.0f));
    __syncthreads();
    float norm = 0.0f;
    for (int k = 0; k < K; ++k) norm += s_w[k];
    const float sc = alpha[5] / norm;

    const uint4* ptr[8];
    float wk[8];
    for (int k = 0; k < K; ++k) {
        ptr[k] = tmp2 + (size_t)knn[n * K + k] * NV;
        wk[k] = s_w[k];
    }
    float* dst = out + (size_t)n * L3;
    if (tid < NV) {
        float acc[8], g[8];
#pragma unroll
        for (int j = 0; j < 8; ++j) acc[j] = 0.0f;
#pragma unroll 8
        for (int k = 0; k < K; ++k) {
            unpack8(ptr[k][tid], g);
#pragma unroll
            for (int j = 0; j < 8; ++j) acc[j] = fmaf(wk[k], g[j], acc[j]);
        }
        const int base = 8 * tid;
#pragma unroll
        for (int j = 0; j < 8; ++j)
            if (base + j < L3) dst[base + j] = sc * acc[j];
    }
}

extern "C" void kernel_launch(void* const* d_in, const int* in_sizes, int n_in,
                              void* d_out, int out_size, void* d_ws, size_t ws_size,
                              hipStream_t stream) {
    const float* cost  = (const float*)d_in[0];
    const int*   knn   = (const int*)d_in[1];
    const float* dist  = (const float*)d_in[2];
    const float* alpha = (const float*)d_in[3];
    float* out = (float*)d_out;

    const int N = in_sizes[0] / L3;
    int K = in_sizes[1] / N;
    if (K > 8) K = 8;

    // workspace: three bf16 volume arrays, each N*NV uint4 (N*4400 bytes)
    uint4* tmp1 = (uint4*)d_ws;
    uint4* tmp2 = tmp1 + (size_t)N * NV;
    uint4* preA = tmp2 + (size_t)N * NV;

    k_smooth1<<<N, NTS, 0, stream>>>(cost, alpha, tmp1, preA);
    k_mid<<<N, NTS, 0, stream>>>(knn, dist, alpha, tmp1, preA, tmp2, K);
    k_out<<<N, NTO, 0, stream>>>(knn, dist, alpha, tmp2, out, K);
}